// Round 1
// baseline (79.986 us; speedup 1.0000x reference)
//
#include <hip/hip_runtime.h>

#define B_  4096
#define NH_ 64
#define NV_ 128

__global__ __launch_bounds__(256)
void cpmte_kernel(const float* __restrict__ muvTE,       // [B,NV]
                  const float* __restrict__ varvhTE,     // [B,NH,NV]
                  const float* __restrict__ varh_diagTE, // [B,NH]
                  const float* __restrict__ varh_diag,   // [B,NH]
                  const float* __restrict__ muh,         // [B,NH]
                  const float* __restrict__ varvh,       // [B,NH,NV]
                  const float* __restrict__ muhTE,       // [B,NH]
                  const float* __restrict__ varvbarTE,   // [B]
                  const int*   __restrict__ nv_p,        // [1]
                  float* __restrict__ out_bTE,   // [B,NV]
                  float* __restrict__ out_wtTE,  // [B,NH,NV]
                  float* __restrict__ out_sig2,  // [B]
                  float* __restrict__ out_muhTE, // [B,NH]
                  float* __restrict__ out_vdTE)  // [B,NH]
{
    const int b   = blockIdx.x;
    const int tid = threadIdx.x;

    __shared__ float s_inner1[NH_]; // vinv*muh
    __shared__ float s_d23[NH_];    // inner2 - inner3
    __shared__ float s_wA[NH_];     // -vinv^2 * vdTE
    __shared__ float s_vinv[NH_];
    __shared__ float s_bpart[8][NV_];
    __shared__ float s_tr[4];

    if (tid < NH_) {
        const int h = tid;
        const float vd   = varh_diag  [(size_t)b * NH_ + h];
        const float vinv = 1.0f / vd;
        const float vdTE = varh_diagTE[(size_t)b * NH_ + h];
        const float m    = muh        [(size_t)b * NH_ + h];
        const float mTE  = muhTE      [(size_t)b * NH_ + h];
        const float inner1 = vinv * m;
        const float inner2 = vinv * vdTE * inner1;
        const float inner3 = vinv * mTE;
        s_inner1[h] = inner1;
        s_d23[h]    = inner2 - inner3;
        s_wA[h]     = -vinv * vinv * vdTE;
        s_vinv[h]   = vinv;
        // passthrough outputs
        out_muhTE[(size_t)b * NH_ + h] = mTE;
        out_vdTE [(size_t)b * NH_ + h] = vdTE;
    }
    __syncthreads();

    const int lane_v = tid & 31;  // float4 index within the 128-wide v dim
    const int grp    = tid >> 5;  // 0..7 — which h-slice this thread covers

    const float4* TEp = (const float4*)(varvhTE + (size_t)b * NH_ * NV_);
    const float4* VHp = (const float4*)(varvh   + (size_t)b * NH_ * NV_);
    float4*       WTp = (float4*)(out_wtTE + (size_t)b * NH_ * NV_);

    float4 accb = make_float4(0.f, 0.f, 0.f, 0.f);
    float  tr   = 0.f;

    #pragma unroll
    for (int k = 0; k < 8; ++k) {
        const int h   = grp * 8 + k;
        const int idx = h * (NV_ / 4) + lane_v;
        const float4 te = TEp[idx];
        const float4 vh = VHp[idx];
        const float i1  = s_inner1[h];
        const float d23 = s_d23[h];
        const float wA  = s_wA[h];
        const float vi  = s_vinv[h];

        // bTE partial: -inner1*TE + (inner2-inner3)*VH
        accb.x += d23 * vh.x - i1 * te.x;
        accb.y += d23 * vh.y - i1 * te.y;
        accb.z += d23 * vh.z - i1 * te.z;
        accb.w += d23 * vh.w - i1 * te.w;

        // wtTE = wA*VH + vinv*TE
        float4 wt;
        wt.x = wA * vh.x + vi * te.x;
        wt.y = wA * vh.y + vi * te.y;
        wt.z = wA * vh.z + vi * te.z;
        wt.w = wA * vh.w + vi * te.w;
        WTp[idx] = wt;

        // tr partial: 2*vinv*TE*VH - vinv^2*vdTE*VH^2 = VH*(2*vi*TE + wA*VH)
        tr += vh.x * (2.f * vi * te.x + wA * vh.x);
        tr += vh.y * (2.f * vi * te.y + wA * vh.y);
        tr += vh.z * (2.f * vi * te.z + wA * vh.z);
        tr += vh.w * (2.f * vi * te.w + wA * vh.w);
    }

    // bTE partials -> LDS
    ((float4*)s_bpart[grp])[lane_v] = accb;

    // tr: wave64 butterfly-free down-reduce
    #pragma unroll
    for (int off = 32; off >= 1; off >>= 1)
        tr += __shfl_down(tr, off, 64);
    if ((tid & 63) == 0) s_tr[tid >> 6] = tr;

    __syncthreads();

    if (tid < NV_) {
        float s = muvTE[(size_t)b * NV_ + tid];
        #pragma unroll
        for (int g = 0; g < 8; ++g) s += s_bpart[g][tid];
        out_bTE[(size_t)b * NV_ + tid] = s;
    }
    if (tid == 0) {
        const float t = s_tr[0] + s_tr[1] + s_tr[2] + s_tr[3];
        out_sig2[b] = (varvbarTE[b] - t) / (float)nv_p[0];
    }
}

extern "C" void kernel_launch(void* const* d_in, const int* in_sizes, int n_in,
                              void* d_out, int out_size, void* d_ws, size_t ws_size,
                              hipStream_t stream) {
    const float* muvTE       = (const float*)d_in[0];
    const float* varvhTE     = (const float*)d_in[1];
    const float* varh_diagTE = (const float*)d_in[2];
    const float* varh_diag   = (const float*)d_in[3];
    const float* muh         = (const float*)d_in[4];
    const float* varvh       = (const float*)d_in[5];
    const float* muhTE       = (const float*)d_in[6];
    const float* varvbarTE   = (const float*)d_in[7];
    const int*   nv_p        = (const int*)d_in[8];

    float* out = (float*)d_out;
    // Flat output layout in return order: bTE, wtTE, sig2TE, muhTE, varh_diagTE
    float* out_bTE   = out;
    float* out_wtTE  = out_bTE  + (size_t)B_ * NV_;
    float* out_sig2  = out_wtTE + (size_t)B_ * NH_ * NV_;
    float* out_muhTE = out_sig2 + (size_t)B_;
    float* out_vdTE  = out_muhTE + (size_t)B_ * NH_;

    dim3 grid(B_), block(256);
    cpmte_kernel<<<grid, block, 0, stream>>>(muvTE, varvhTE, varh_diagTE, varh_diag,
                                             muh, varvh, muhTE, varvbarTE, nv_p,
                                             out_bTE, out_wtTE, out_sig2,
                                             out_muhTE, out_vdTE);
}

// Round 3
// 66.375 us; speedup vs baseline: 1.2051x; 1.2051x over previous
//
#include <hip/hip_runtime.h>

#define B_  4096
#define NH_ 64
#define NV_ 128

typedef float nfloat4 __attribute__((ext_vector_type(4)));

__global__ __launch_bounds__(256, 3)
void cpmte_kernel(const float* __restrict__ muvTE,       // [B,NV]
                  const float* __restrict__ varvhTE,     // [B,NH,NV]
                  const float* __restrict__ varh_diagTE, // [B,NH]
                  const float* __restrict__ varh_diag,   // [B,NH]
                  const float* __restrict__ muh,         // [B,NH]
                  const float* __restrict__ varvh,       // [B,NH,NV]
                  const float* __restrict__ muhTE,       // [B,NH]
                  const float* __restrict__ varvbarTE,   // [B]
                  const int*   __restrict__ nv_p,        // [1]
                  float* __restrict__ out_bTE,   // [B,NV]
                  float* __restrict__ out_wtTE,  // [B,NH,NV]
                  float* __restrict__ out_sig2,  // [B]
                  float* __restrict__ out_muhTE, // [B,NH]
                  float* __restrict__ out_vdTE)  // [B,NH]
{
    const int b      = blockIdx.x;
    const int tid    = threadIdx.x;
    const int lane_v = tid & 31;  // float4 index within 128-wide v dim
    const int grp    = tid >> 5;  // 0..7 — which h-slice this thread covers

    const nfloat4* TEp = (const nfloat4*)(varvhTE + (size_t)b * NH_ * NV_);
    const nfloat4* VHp = (const nfloat4*)(varvh   + (size_t)b * NH_ * NV_);
    nfloat4*       WTp = (nfloat4*)(out_wtTE + (size_t)b * NH_ * NV_);

    // --- Prefetch ALL streaming loads BEFORE the coefficient barrier ---
    nfloat4 te[8], vh[8];
    #pragma unroll
    for (int k = 0; k < 8; ++k) {
        const int idx = (grp * 8 + k) * (NV_ / 4) + lane_v;
        te[k] = TEp[idx];
        vh[k] = VHp[idx];
    }
    float muv = 0.f;
    if (tid < NV_) muv = muvTE[(size_t)b * NV_ + tid];

    __shared__ float s_i1[NH_];   // vinv*muh
    __shared__ float s_d23[NH_];  // inner2 - inner3
    __shared__ float s_wA[NH_];   // -vinv^2 * vdTE
    __shared__ float s_vinv[NH_];
    __shared__ float s_bpart[8][NV_];
    __shared__ float s_tr[4];

    if (tid < NH_) {
        const int h = tid;
        const float vd   = varh_diag  [(size_t)b * NH_ + h];
        const float vinv = 1.0f / vd;
        const float vdTE = varh_diagTE[(size_t)b * NH_ + h];
        const float m    = muh        [(size_t)b * NH_ + h];
        const float mTE  = muhTE      [(size_t)b * NH_ + h];
        const float inner1 = vinv * m;
        const float inner2 = vinv * vdTE * inner1;
        const float inner3 = vinv * mTE;
        s_i1[h]   = inner1;
        s_d23[h]  = inner2 - inner3;
        s_wA[h]   = -vinv * vinv * vdTE;
        s_vinv[h] = vinv;
        out_muhTE[(size_t)b * NH_ + h] = mTE;
        out_vdTE [(size_t)b * NH_ + h] = vdTE;
    }
    __syncthreads();

    float accbx = 0.f, accby = 0.f, accbz = 0.f, accbw = 0.f;
    float tr = 0.f;

    #pragma unroll
    for (int k = 0; k < 8; ++k) {
        const int h   = grp * 8 + k;
        const int idx = h * (NV_ / 4) + lane_v;
        const float i1  = s_i1[h];
        const float d23 = s_d23[h];
        const float wA  = s_wA[h];
        const float vi  = s_vinv[h];
        const nfloat4 t4 = te[k];
        const nfloat4 v4 = vh[k];

        accbx += d23 * v4.x - i1 * t4.x;
        accby += d23 * v4.y - i1 * t4.y;
        accbz += d23 * v4.z - i1 * t4.z;
        accbw += d23 * v4.w - i1 * t4.w;

        // wtTE = wA*VH + vinv*TE — non-temporal streaming write so the
        // 134 MB output doesn't evict the L3-resident input set.
        nfloat4 wt;
        wt.x = wA * v4.x + vi * t4.x;
        wt.y = wA * v4.y + vi * t4.y;
        wt.z = wA * v4.z + vi * t4.z;
        wt.w = wA * v4.w + vi * t4.w;
        __builtin_nontemporal_store(wt, &WTp[idx]);

        // tr partial: VH*(2*vi*TE + wA*VH)
        tr += v4.x * (2.f * vi * t4.x + wA * v4.x);
        tr += v4.y * (2.f * vi * t4.y + wA * v4.y);
        tr += v4.z * (2.f * vi * t4.z + wA * v4.z);
        tr += v4.w * (2.f * vi * t4.w + wA * v4.w);
    }

    {
        nfloat4 accb = {accbx, accby, accbz, accbw};
        ((nfloat4*)s_bpart[grp])[lane_v] = accb;
    }

    #pragma unroll
    for (int off = 32; off >= 1; off >>= 1)
        tr += __shfl_down(tr, off, 64);
    if ((tid & 63) == 0) s_tr[tid >> 6] = tr;

    __syncthreads();

    if (tid < NV_) {
        float s = muv;
        #pragma unroll
        for (int g = 0; g < 8; ++g) s += s_bpart[g][tid];
        out_bTE[(size_t)b * NV_ + tid] = s;
    }
    if (tid == 0) {
        const float t = s_tr[0] + s_tr[1] + s_tr[2] + s_tr[3];
        out_sig2[b] = (varvbarTE[b] - t) / (float)nv_p[0];
    }
}

extern "C" void kernel_launch(void* const* d_in, const int* in_sizes, int n_in,
                              void* d_out, int out_size, void* d_ws, size_t ws_size,
                              hipStream_t stream) {
    const float* muvTE       = (const float*)d_in[0];
    const float* varvhTE     = (const float*)d_in[1];
    const float* varh_diagTE = (const float*)d_in[2];
    const float* varh_diag   = (const float*)d_in[3];
    const float* muh         = (const float*)d_in[4];
    const float* varvh       = (const float*)d_in[5];
    const float* muhTE       = (const float*)d_in[6];
    const float* varvbarTE   = (const float*)d_in[7];
    const int*   nv_p        = (const int*)d_in[8];

    float* out = (float*)d_out;
    float* out_bTE   = out;
    float* out_wtTE  = out_bTE  + (size_t)B_ * NV_;
    float* out_sig2  = out_wtTE + (size_t)B_ * NH_ * NV_;
    float* out_muhTE = out_sig2 + (size_t)B_;
    float* out_vdTE  = out_muhTE + (size_t)B_ * NH_;

    dim3 grid(B_), block(256);
    cpmte_kernel<<<grid, block, 0, stream>>>(muvTE, varvhTE, varh_diagTE, varh_diag,
                                             muh, varvh, muhTE, varvbarTE, nv_p,
                                             out_bTE, out_wtTE, out_sig2,
                                             out_muhTE, out_vdTE);
}